// Round 4
// baseline (868.050 us; speedup 1.0000x reference)
//
#include <hip/hip_runtime.h>
#include <cfloat>
#include <cstddef>

#define B_ 32
#define C_ 8192
#define D_ 256
#define K_ 512
#define NCH 64
#define CPB (C_ / NCH) /* 128 c's per chunk */

typedef float f4n __attribute__((ext_vector_type(4)));

__device__ __forceinline__ unsigned fmapk(float f) {
    unsigned u = __float_as_uint(f);
    return (u & 0x80000000u) ? ~u : (u | 0x80000000u);
}

// Bit-deterministic key for class c: |w_c|^2 - 2 s.w_c, mapped to sortable uint.
// Fixed fmaf chain -> identical bits at every call site (radix passes + ties).
__device__ __forceinline__ unsigned keyc(const float* __restrict__ weight,
                                         const float* s_s, int c) {
    const f4n* wr = (const f4n*)(weight + (size_t)c * D_);
    const f4n* sr = (const f4n*)s_s;
    float dot = 0.f, nsq = 0.f;
#pragma unroll 8
    for (int d4 = 0; d4 < D_ / 4; d4++) {
        f4n w = wr[d4], sv = sr[d4];
        dot = fmaf(w.x, sv.x, dot); dot = fmaf(w.y, sv.y, dot);
        dot = fmaf(w.z, sv.z, dot); dot = fmaf(w.w, sv.w, dot);
        nsq = fmaf(w.x, w.x, nsq); nsq = fmaf(w.y, w.y, nsq);
        nsq = fmaf(w.z, w.z, nsq); nsq = fmaf(w.w, w.w, nsq);
    }
    return fmapk(nsq - 2.0f * dot);
}

// ---------------- k0: zero the arrival counters (cnt[0..B_]) ------------------
__global__ __launch_bounds__(64) void k0_init(unsigned* __restrict__ cnt) {
    if (threadIdx.x <= B_) cnt[threadIdx.x] = 0u;
}

// ---------------- fused: stream-reduce + finisher combine + det + scalar ------
// grid = B*NCH = 2048 blocks x 4 waves; LDS 12.3 KiB -> 8 blocks/CU resident
// (32 waves/CU). Phase-1 row order is rotated per block ((i+7*blk)&31) so
// concurrent global addresses spread across the HBM channel-interleave bits
// instead of camping in lockstep. Last-arrival block per b finishes that b;
// last finisher overall writes the scalar. Det path (never taken on this data,
// gated block-uniformly) recomputes keys on the fly -> no 32 KiB LDS key array.
// No spin-waits anywhere -> no deadlock possible.
__global__ __launch_bounds__(256, 8) void k_fused(const float* __restrict__ acd,
                                                  const float* __restrict__ weight,
                                                  const float* __restrict__ mu,
                                                  const float* __restrict__ var,
                                                  const int* __restrict__ labels,
                                                  float* __restrict__ psum,
                                                  float* __restrict__ pm1,
                                                  float* __restrict__ pm2,
                                                  double* __restrict__ partial,
                                                  unsigned* __restrict__ cnt,
                                                  float* __restrict__ out) {
    const int t = threadIdx.x;
    const int blk = blockIdx.x;
    const int b = blk / NCH, ch = blk % NCH;

    // ---- LDS union (12,288 B): phase-1 staging aliases det-path scratch ------
    __shared__ __align__(16) char smem[12288];
    f4n* ls = (f4n*)smem;                       // [256] 4 KiB   phase 1
    f4n* l1 = (f4n*)(smem + 4096);              // [256] 4 KiB   phase 1
    f4n* l2 = (f4n*)(smem + 8192);              // [256] 4 KiB   phase 1
    float*    s_s  = (float*)smem;              // [D_]  1 KiB   det
    unsigned* hist = (unsigned*)(smem + 1024);  // [256] 1 KiB   det
    unsigned* scan = (unsigned*)(smem + 2048);  // [256] 1 KiB   det
    int*      sel  = (int*)(smem + 3072);       // [K_]  2 KiB   det
    double*   red  = (double*)smem;             // [256] 2 KiB   final reduce
    __shared__ unsigned s_fin, s_anyo, s_last, sh_pref, sh_want, sh_nsel;

    // ================= phase 1: chunk column-reduce (sum, min, 2nd-min) ======
    {
        const int d4 = t & 63;     // f4n column within D (64 x 4 floats = 256)
        const int coff = t >> 6;   // 4-way row split within the chunk
        const int rot = (blk * 7) & 31;   // de-camping rotation (7 coprime 32)
        const f4n* src = (const f4n*)(acd + ((size_t)b * C_ + (size_t)ch * CPB) * D_);

        f4n s  = (f4n){0.f, 0.f, 0.f, 0.f};
        f4n m1 = (f4n){FLT_MAX, FLT_MAX, FLT_MAX, FLT_MAX};
        f4n m2 = m1;

#define UPD3(f) { s.f += x.f; float mx = fmaxf(m1.f, x.f); m2.f = fminf(m2.f, mx); m1.f = fminf(m1.f, x.f); }
#pragma unroll 4
        for (int i = 0; i < CPB / 4; i++) {
            const int r = (((i + rot) & 31) << 2) + coff;
            f4n x = src[(size_t)r * 64 + d4];
            UPD3(x) UPD3(y) UPD3(z) UPD3(w)
        }
#undef UPD3

        ls[t] = s; l1[t] = m1; l2[t] = m2;
        __syncthreads();

        if (t < 64) {
            f4n S = ls[t], M1 = l1[t], M2 = l2[t];
#define CMB(f) { S.f += s2.f; float mx = fmaxf(M1.f, a1.f); M2.f = fminf(fminf(M2.f, a2.f), mx); M1.f = fminf(M1.f, a1.f); }
#pragma unroll
            for (int j = 64; j < 256; j += 64) {
                f4n s2 = ls[t + j], a1 = l1[t + j], a2 = l2[t + j];
                CMB(x) CMB(y) CMB(z) CMB(w)
            }
#undef CMB
            size_t o = ((size_t)b * NCH + ch) * 64 + t;
            ((f4n*)psum)[o] = S;
            ((f4n*)pm1)[o] = M1;
            ((f4n*)pm2)[o] = M2;
        }
    }

    // ================= arrival: last block for this b becomes finisher =======
    __threadfence();            // release our partial stores (device scope)
    __syncthreads();
    if (t == 0) {
        s_fin = (atomicAdd(&cnt[b], 1u) == NCH - 1) ? 1u : 0u;
        s_last = 0u;
    }
    __syncthreads();
    if (s_fin == 0u) return;
    __threadfence();            // acquire: other blocks' partials now visible

    // ================= phase 2 (finisher only): combine + dens/tot/overly ====
    float sum = 0.f, m1 = FLT_MAX, m2 = FLT_MAX;
    for (int c2 = 0; c2 < NCH; c2++) {
        size_t o = ((size_t)b * NCH + c2) * D_ + t;
        float cs = psum[o], c1v = pm1[o], c2v = pm2[o];
        sum += cs;
        m2 = fminf(fminf(m2, c2v), fmaxf(m1, c1v));
        m1 = fminf(m1, c1v);
    }
    const int lab = labels[b];
    const float sw = weight[(size_t)lab * D_ + t];
    const float muv = mu[b * D_ + t];
    const float v = var[b * D_ + t];
    const float diff = sw - muv;
    const float dens = expf(-(diff * diff) / (2.0f * v));
    const float tot = fmaxf(sum, 1e-8f);
    const float o_ = (m2 - m1 >= 0.2f * tot) ? 1.0f : 0.0f;

    double contrib = (double)dens / (double)tot *
                     ((double)C_ - (double)(C_ - 1) * (double)o_);

    if (t == 0) s_anyo = 0u;
    __syncthreads();            // also closes phase-1 LDS lifetime
    if (o_ != 0.0f) atomicOr(&s_anyo, 1u);
    __syncthreads();

    if (s_anyo != 0u) {         // block-uniform -> __syncthreads inside is legal
        s_s[t] = sw;
        if (t == 0) { sh_pref = 0u; sh_want = K_; sh_nsel = 0u; }
        __syncthreads();

        // 4-pass radix select of the 512th-smallest key (keys recomputed)
        for (int pass = 0; pass < 4; pass++) {
            const int shift = 24 - 8 * pass;
            hist[t] = 0u;
            __syncthreads();
            const unsigned pref = sh_pref;
            const unsigned pmask = (pass == 0) ? 0u : (0xFFFFFFFFu << (shift + 8));
            for (int c = t; c < C_; c += 256) {
                unsigned u = keyc(weight, s_s, c);
                if ((u & pmask) == (pref & pmask)) atomicAdd(&hist[(u >> shift) & 255u], 1u);
            }
            __syncthreads();
            unsigned h = hist[t];
            scan[t] = h;
            __syncthreads();
            for (int off = 1; off < 256; off <<= 1) {
                unsigned x = (t >= off) ? scan[t - off] : 0u;
                __syncthreads();
                scan[t] += x;
                __syncthreads();
            }
            const unsigned want = sh_want;
            const unsigned incl = scan[t], excl = incl - h;
            if (incl >= want && excl < want) {   // exactly one t satisfies this
                sh_pref = pref | ((unsigned)t << shift);
                sh_want = want - excl;
            }
            __syncthreads();
        }

        const unsigned Kk = sh_pref, quota = sh_want;
        for (int c = t; c < C_; c += 256) {
            unsigned u = keyc(weight, s_s, c);
            bool take = (u < Kk);
            if (!take && u == Kk) {
                unsigned r = 0;
                for (int j = 0; j < c; j++)
                    if (keyc(weight, s_s, j) == Kk) r++;
                take = (r < quota);   // lowest-index ties first (jax top_k order)
            }
            if (take) {
                unsigned s2i = atomicAdd(&sh_nsel, 1u);
                if (s2i < (unsigned)K_) sel[s2i] = c;   // defensive bound
            }
        }
        __syncthreads();

        // total_det[d=t] = sum over 512 selected classes of exp densities
        const float nh = -0.5f / v;
        float acc = 0.f;
        for (int k = 0; k < K_; k++) {
            float w = weight[(size_t)sel[k] * D_ + t];   // lanes d coalesced
            float df = w - muv;
            acc += expf(df * df * nh);
        }
        double td = fmax((double)acc, 1e-8);
        contrib -= (double)dens / td * (double)(C_ - 1) * (double)o_;
        __syncthreads();        // det LDS lifetime ends before red aliases smem
    }

    // ================= per-b reduce, then last finisher writes the scalar ====
    red[t] = contrib;
    __syncthreads();
    for (int s2 = 128; s2 > 0; s2 >>= 1) {
        if (t < s2) red[t] += red[t + s2];
        __syncthreads();
    }
    if (t == 0) {
        partial[b] = red[0];
        __threadfence();        // release partial[b]
        s_last = (atomicAdd(&cnt[B_], 1u) == B_ - 1) ? 1u : 0u;
    }
    __syncthreads();
    if (s_last != 0u && t < 64) {
        __threadfence();        // acquire all partial[b]
        double v2 = (t < B_) ? partial[t] : 0.0;
#pragma unroll
        for (int off = 32; off > 0; off >>= 1) v2 += __shfl_down(v2, off);
        if (t == 0) out[0] = (float)(v2 / ((double)B_ * (double)C_ * (double)D_));
    }
}

extern "C" void kernel_launch(void* const* d_in, const int* in_sizes, int n_in,
                              void* d_out, int out_size, void* d_ws, size_t ws_size,
                              hipStream_t stream) {
    const float* weight = (const float*)d_in[0];
    const float* mu     = (const float*)d_in[1];
    const float* var    = (const float*)d_in[2];
    const float* acd    = (const float*)d_in[3];
    const int*   labels = (const int*)d_in[4];
    float* out = (float*)d_out;

    char* ws = (char*)d_ws;
    const size_t np = (size_t)B_ * NCH * D_;   // 524288 floats per partial array
    float* psum = (float*)ws;
    float* pm1  = psum + np;
    float* pm2  = pm1 + np;
    double* partial = (double*)(pm2 + np);     // 3*np*4 B offset -> 8B aligned
    unsigned* cnt = (unsigned*)(partial + B_); // [B_] per-b arrivals + [1] global

    k0_init<<<1, 64, 0, stream>>>(cnt);
    k_fused<<<B_ * NCH, 256, 0, stream>>>(acd, weight, mu, var, labels,
                                          psum, pm1, pm2, partial, cnt, out);
}

// Round 5
// 451.129 us; speedup vs baseline: 1.9242x; 1.9242x over previous
//
#include <hip/hip_runtime.h>
#include <cfloat>
#include <cstddef>

#define B_ 32
#define C_ 8192
#define D_ 256
#define K_ 512
#define NCH 64
#define CPB (C_ / NCH) /* 128 c's per chunk */

typedef float f4n __attribute__((ext_vector_type(4)));  // native vec for nontemporal builtin

// ---------------- k1: column reduce over C (sum, min, 2nd-min) ----------------
// grid = B*NCH = 2048 blocks x 4 waves. Wave w owns 32 contiguous rows of the
// 128-row chunk; each loop body issues EIGHT independent nontemporal 16B loads
// before any use (named regs -> one 8-wide global_load_dwordx4 clause -> 8 KiB
// in flight per wave). This is the MLP fix for the latency-bound stream: round
// 3/4 counters showed only 1-3 wave-loads in flight per CU (1.3 TB/s eff; 518us
// even when acd was fully cache-resident). No launch_bounds min-waves: round 4
// proved capping VGPRs at 32 serializes the loads (VGPR 56->32, 2.6x slower).
__global__ __launch_bounds__(256) void k1_colreduce(const float* __restrict__ acd,
                                                    float* __restrict__ psum,
                                                    float* __restrict__ pm1,
                                                    float* __restrict__ pm2) {
    const int t = threadIdx.x;
    const int b = blockIdx.x / NCH, ch = blockIdx.x % NCH;
    const int d4 = t & 63;     // f4n column within D (64 x 4 floats = 256)
    const int w = t >> 6;      // wave id 0..3 -> rows [32w, 32w+32)

    const f4n* src = (const f4n*)(acd + ((size_t)b * C_ + (size_t)ch * CPB) * D_);
    const f4n* p = src + ((size_t)(w * 32) * 64 + d4);

    f4n s  = (f4n){0.f, 0.f, 0.f, 0.f};
    f4n m1 = (f4n){FLT_MAX, FLT_MAX, FLT_MAX, FLT_MAX};
    f4n m2 = m1;

#define UPD3(f, xv) { s.f += xv.f; float mx = fmaxf(m1.f, xv.f); m2.f = fminf(m2.f, mx); m1.f = fminf(m1.f, xv.f); }
#define UPD(xv) UPD3(x, xv) UPD3(y, xv) UPD3(z, xv) UPD3(w, xv)
    for (int bt = 0; bt < 4; bt++, p += 8 * 64) {
        f4n x0 = __builtin_nontemporal_load(p + 0 * 64);
        f4n x1 = __builtin_nontemporal_load(p + 1 * 64);
        f4n x2 = __builtin_nontemporal_load(p + 2 * 64);
        f4n x3 = __builtin_nontemporal_load(p + 3 * 64);
        f4n x4 = __builtin_nontemporal_load(p + 4 * 64);
        f4n x5 = __builtin_nontemporal_load(p + 5 * 64);
        f4n x6 = __builtin_nontemporal_load(p + 6 * 64);
        f4n x7 = __builtin_nontemporal_load(p + 7 * 64);
        UPD(x0) UPD(x1) UPD(x2) UPD(x3)
        UPD(x4) UPD(x5) UPD(x6) UPD(x7)
    }
#undef UPD
#undef UPD3

    __shared__ f4n ls[256];
    __shared__ f4n l1[256];
    __shared__ f4n l2[256];
    ls[t] = s; l1[t] = m1; l2[t] = m2;
    __syncthreads();

    if (t < 64) {
        f4n S = ls[t], M1 = l1[t], M2 = l2[t];
#define CMB(f) { S.f += s2.f; float mx = fmaxf(M1.f, a1.f); M2.f = fminf(fminf(M2.f, a2.f), mx); M1.f = fminf(M1.f, a1.f); }
#pragma unroll
        for (int j = 64; j < 256; j += 64) {
            f4n s2 = ls[t + j], a1 = l1[t + j], a2 = l2[t + j];
            CMB(x) CMB(y) CMB(z) CMB(w)
        }
#undef CMB
        size_t o = ((size_t)b * NCH + ch) * 64 + t;
        ((f4n*)psum)[o] = S;
        ((f4n*)pm1)[o] = M1;
        ((f4n*)pm2)[o] = M2;
    }
}

// ------- k2: combine chunks -> dens/tot/overly in registers; fused det path ---
// One block per b (d = threadIdx). The det path (keys + radix-select-512 +
// total_det) runs inline behind a block-uniform LDS flag — executes only when
// some d of THIS b has overly != 0 (never on this data, but must stay correct).
__device__ __forceinline__ unsigned fmapk(float f) {
    unsigned u = __float_as_uint(f);
    return (u & 0x80000000u) ? ~u : (u | 0x80000000u);
}

__global__ __launch_bounds__(256) void k2_fused(const float* __restrict__ psum,
                                                const float* __restrict__ pm1,
                                                const float* __restrict__ pm2,
                                                const float* __restrict__ weight,
                                                const float* __restrict__ mu,
                                                const float* __restrict__ var,
                                                const int* __restrict__ labels,
                                                double* __restrict__ partial) {
    const int b = blockIdx.x, t = threadIdx.x;

    float sum = 0.f, m1 = FLT_MAX, m2 = FLT_MAX;
    for (int ch = 0; ch < NCH; ch++) {
        size_t o = ((size_t)b * NCH + ch) * D_ + t;
        float cs = psum[o], c1 = pm1[o], c2 = pm2[o];
        sum += cs;
        m2 = fminf(fminf(m2, c2), fmaxf(m1, c1));
        m1 = fminf(m1, c1);
    }
    const int lab = labels[b];
    const float sw = weight[(size_t)lab * D_ + t];
    const float muv = mu[b * D_ + t];
    const float v = var[b * D_ + t];
    const float diff = sw - muv;
    const float dens = expf(-(diff * diff) / (2.0f * v));
    const float tot = fmaxf(sum, 1e-8f);
    const float o_ = (m2 - m1 >= 0.2f * tot) ? 1.0f : 0.0f;

    // non-det term: dens/tot * (C - (C-1)*o)
    double contrib = (double)dens / (double)tot *
                     ((double)C_ - (double)(C_ - 1) * (double)o_);

    __shared__ unsigned anyo;
    if (t == 0) anyo = 0u;
    __syncthreads();
    if (o_ != 0.0f) atomicOr(&anyo, 1u);
    __syncthreads();

    if (anyo != 0u) {   // block-uniform -> __syncthreads inside is legal
        __shared__ unsigned kl[C_];      // 32 KiB mapped keys
        __shared__ float s_s[D_];
        __shared__ unsigned hist[256];
        __shared__ unsigned scan[256];
        __shared__ int sel[K_];
        __shared__ unsigned sh_pref, sh_want, sh_nsel;

        s_s[t] = sw;                     // sample weight row (d = t)
        if (t == 0) { sh_pref = 0u; sh_want = K_; sh_nsel = 0u; }
        __syncthreads();

        // keys: |w_c|^2 - 2 s.w_c
        for (int c = t; c < C_; c += 256) {
            const f4n* wr = (const f4n*)(weight + (size_t)c * D_);
            const f4n* sr = (const f4n*)s_s;
            float dot = 0.f, nsq = 0.f;
#pragma unroll 8
            for (int d4 = 0; d4 < D_ / 4; d4++) {
                f4n wv = wr[d4], sv = sr[d4];
                dot += wv.x * sv.x + wv.y * sv.y + wv.z * sv.z + wv.w * sv.w;
                nsq += wv.x * wv.x + wv.y * wv.y + wv.z * wv.z + wv.w * wv.w;
            }
            kl[c] = fmapk(nsq - 2.0f * dot);
        }
        __syncthreads();

        // 4-pass radix select of the 512th-smallest mapped key
        for (int pass = 0; pass < 4; pass++) {
            const int shift = 24 - 8 * pass;
            hist[t] = 0u;
            __syncthreads();
            const unsigned pref = sh_pref;
            const unsigned pmask = (pass == 0) ? 0u : (0xFFFFFFFFu << (shift + 8));
            for (int c = t; c < C_; c += 256) {
                unsigned u = kl[c];
                if ((u & pmask) == (pref & pmask)) atomicAdd(&hist[(u >> shift) & 255u], 1u);
            }
            __syncthreads();
            unsigned h = hist[t];
            scan[t] = h;
            __syncthreads();
            for (int off = 1; off < 256; off <<= 1) {
                unsigned x = (t >= off) ? scan[t - off] : 0u;
                __syncthreads();
                scan[t] += x;
                __syncthreads();
            }
            const unsigned want = sh_want;
            const unsigned incl = scan[t], excl = incl - h;
            if (incl >= want && excl < want) {   // exactly one t satisfies this
                sh_pref = pref | ((unsigned)t << shift);
                sh_want = want - excl;
            }
            __syncthreads();
        }

        const unsigned Kk = sh_pref, quota = sh_want;
        for (int c = t; c < C_; c += 256) {
            unsigned u = kl[c];
            bool take = (u < Kk);
            if (!take && u == Kk) {
                unsigned r = 0;
                for (int j = 0; j < c; j++)
                    if (kl[j] == Kk) r++;
                take = (r < quota);   // lowest-index ties first (jax top_k order)
            }
            if (take) {
                unsigned s2i = atomicAdd(&sh_nsel, 1u);
                if (s2i < (unsigned)K_) sel[s2i] = c;   // defensive bound
            }
        }
        __syncthreads();

        // total_det[d=t] = sum over 512 selected classes of exp densities
        const float nh = -0.5f / v;
        float acc = 0.f;
        for (int k = 0; k < K_; k++) {
            float wv = weight[(size_t)sel[k] * D_ + t];   // lanes d coalesced
            float df = wv - muv;
            acc += expf(df * df * nh);
        }
        double td = fmax((double)acc, 1e-8);
        contrib -= (double)dens / td * (double)(C_ - 1) * (double)o_;
    }

    // block reduce 256 doubles -> partial[b]
    __shared__ double red[256];
    red[t] = contrib;
    __syncthreads();
    for (int s2 = 128; s2 > 0; s2 >>= 1) {
        if (t < s2) red[t] += red[t + s2];
        __syncthreads();
    }
    if (t == 0) partial[b] = red[0];
}

// ---------------- k3: sum 32 per-b partials, scale, write scalar --------------
__global__ __launch_bounds__(64) void k3_final(const double* __restrict__ partial,
                                               float* __restrict__ out) {
    const int t = threadIdx.x;
    double v = (t < B_) ? partial[t] : 0.0;
#pragma unroll
    for (int off = 32; off > 0; off >>= 1) v += __shfl_down(v, off);
    if (t == 0) out[0] = (float)(v / ((double)B_ * (double)C_ * (double)D_));
}

extern "C" void kernel_launch(void* const* d_in, const int* in_sizes, int n_in,
                              void* d_out, int out_size, void* d_ws, size_t ws_size,
                              hipStream_t stream) {
    const float* weight = (const float*)d_in[0];
    const float* mu     = (const float*)d_in[1];
    const float* var    = (const float*)d_in[2];
    const float* acd    = (const float*)d_in[3];
    const int*   labels = (const int*)d_in[4];
    float* out = (float*)d_out;

    char* ws = (char*)d_ws;
    const size_t np = (size_t)B_ * NCH * D_;   // 524288 floats per partial array
    float* psum = (float*)ws;
    float* pm1  = psum + np;
    float* pm2  = pm1 + np;
    double* partial = (double*)(pm2 + np);     // 3*np*4 B offset -> 8B aligned

    k1_colreduce<<<B_ * NCH, 256, 0, stream>>>(acd, psum, pm1, pm2);
    k2_fused<<<B_, 256, 0, stream>>>(psum, pm1, pm2, weight, mu, var, labels, partial);
    k3_final<<<1, 64, 0, stream>>>(partial, out);
}